// Round 6
// baseline (277.376 us; speedup 1.0000x reference)
//
#include <hip/hip_runtime.h>
#include <hip/hip_bf16.h>

// Problem constants (fixed by the reference)
#define DDIM   200
#define CSEG   50000
#define TTOT   1000000
#define BROWS  1024
#define KPAD   224      // 7 * 32 (K padded for mfma 16x16x32)
#define NTILE  64
#define NT     782      // ceil(50000/64)
#define NPAD   50048    // NT*64
#define MTILES 4        // 1024 / 256 (M-tile = 256 halves Hb L2 re-reads)
#define GEMM_BLOCKS (NT * MTILES)   // 3128 = 8 * 391 exactly
#define LDSROW 232      // padded LDS row stride (bf16 units): breaks bank conflicts

typedef __attribute__((ext_vector_type(8))) __bf16 bf16x8;
typedef __attribute__((ext_vector_type(4))) float  f32x4;
typedef unsigned short u16;
typedef __attribute__((ext_vector_type(8))) unsigned short u16x8;
typedef __attribute__((ext_vector_type(4))) unsigned short u16x4;

// ws layout (bytes)
#define WS_XB    0u
#define WS_HB    458752u
#define WS_PART  (WS_HB + 22421504u)
#define WS_INV   (WS_PART + 3203072u)
#define WS_START (WS_INV + 4096u)
#define WS_EBF   (WS_START + 200704u)
#define WS_TOTAL_BF16 ((size_t)WS_EBF + 160000000u)   // + bf16 embed table

__device__ inline u16 f2bf(float f) {
  unsigned u = __float_as_uint(f);
  u += 0x7FFFu + ((u >> 16) & 1u);   // round-to-nearest-even
  return (u16)(u >> 16);
}
__device__ inline float bf2f(u16 h) {
  return __uint_as_float(((unsigned)h) << 16);
}

// ---- fused: segment starts + x->bf16 + (optional) embed f32->bf16 -----------
__global__ __launch_bounds__(256) void prep_all_kernel(const int* __restrict__ sid,
                                                       int* __restrict__ start,
                                                       const float* __restrict__ x,
                                                       u16* __restrict__ xb,
                                                       const float* __restrict__ embed,
                                                       u16* __restrict__ ebf,
                                                       int do_conv) {
  const int gtid = blockIdx.x * 256 + threadIdx.x;
  // part 1: segment boundary detection (sorted sid)
  if (gtid < TTOT) {
    const int cur = sid[gtid];
    const int prev = (gtid == 0) ? -1 : sid[gtid - 1];
    for (int c = prev + 1; c <= cur; ++c) start[c] = gtid;
    if (gtid == TTOT - 1) {
      for (int c = cur + 1; c <= CSEG; ++c) start[c] = TTOT;
    }
  }
  // part 2: x -> bf16 K-padded
  if (gtid < BROWS * 56) {
    const int row = gtid / 56;
    const int col = (gtid % 56) * 4;
    ushort4 o = make_ushort4(0, 0, 0, 0);
    if (col < DDIM) {
      const float4 v = *reinterpret_cast<const float4*>(x + (size_t)row * DDIM + col);
      o = make_ushort4(f2bf(v.x), f2bf(v.y), f2bf(v.z), f2bf(v.w));
    }
    *reinterpret_cast<ushort4*>(xb + (size_t)row * KPAD + col) = o;
  }
  // part 3: embed table f32 -> bf16 (L3-resident afterwards), grid-stride
  if (do_conv) {
    const long long n4 = (long long)400000 * DDIM / 4;   // 20M float4
    const long long stride = (long long)gridDim.x * 256;
    for (long long i = gtid; i < n4; i += stride) {
      const f32x4 v = __builtin_nontemporal_load(reinterpret_cast<const f32x4*>(embed) + i);
      u16x4 o;
      o.x = f2bf(v.x); o.y = f2bf(v.y); o.z = f2bf(v.z); o.w = f2bf(v.w);
      *(reinterpret_cast<u16x4*>(ebf) + i) = o;
    }
  }
}

// ---- ragged gather (bf16 table) + segment sum -> Hb -------------------------
__global__ __launch_bounds__(256) void seg_sum_bf16_kernel(const u16* __restrict__ ebf,
                                                           const int* __restrict__ aid,
                                                           const int* __restrict__ start,
                                                           u16* __restrict__ Hb) {
  const int wave = threadIdx.x >> 6;
  const int lane = threadIdx.x & 63;
  const int c = blockIdx.x * 4 + wave;
  if (c >= NPAD || lane >= 56) return;
  const int col = lane * 4;
  const bool act = (col < DDIM);
  float4 a[8];
#pragma unroll
  for (int j = 0; j < 8; ++j) a[j] = make_float4(0.f, 0.f, 0.f, 0.f);
  if (c < CSEG && act) {
    const int s = start[c], e = start[c + 1];
    for (int t = s; t < e; t += 8) {
      int   idx[8];
      float msk[8];
#pragma unroll
      for (int j = 0; j < 8; ++j) {
        const int tt = t + j;
        const bool ok = (tt < e);
        idx[j] = aid[ok ? tt : s];
        msk[j] = ok ? 1.f : 0.f;
      }
#pragma unroll
      for (int j = 0; j < 8; ++j) {
        const ushort4 v = *reinterpret_cast<const ushort4*>(
            ebf + (size_t)idx[j] * DDIM + col);
        a[j].x = fmaf(msk[j], bf2f(v.x), a[j].x);
        a[j].y = fmaf(msk[j], bf2f(v.y), a[j].y);
        a[j].z = fmaf(msk[j], bf2f(v.z), a[j].z);
        a[j].w = fmaf(msk[j], bf2f(v.w), a[j].w);
      }
    }
#pragma unroll
    for (int j = 4; j < 8; ++j) {
      a[j - 4].x += a[j].x; a[j - 4].y += a[j].y;
      a[j - 4].z += a[j].z; a[j - 4].w += a[j].w;
    }
    a[0].x += a[1].x + a[2].x + a[3].x;
    a[0].y += a[1].y + a[2].y + a[3].y;
    a[0].z += a[1].z + a[2].z + a[3].z;
    a[0].w += a[1].w + a[2].w + a[3].w;
  }
  const ushort4 o = (c < CSEG && act)
      ? make_ushort4(f2bf(a[0].x), f2bf(a[0].y), f2bf(a[0].z), f2bf(a[0].w))
      : make_ushort4(0, 0, 0, 0);
  *reinterpret_cast<ushort4*>(Hb + (size_t)c * KPAD + col) = o;
}

// ---- fallback f32 gather (ws too small for bf16 table) ----------------------
__global__ __launch_bounds__(256) void seg_sum_kernel(const float* __restrict__ embed,
                                                      const int* __restrict__ aid,
                                                      const int* __restrict__ start,
                                                      u16* __restrict__ Hb) {
  const int wave = threadIdx.x >> 6;
  const int lane = threadIdx.x & 63;
  const int c = blockIdx.x * 4 + wave;
  if (c >= NPAD || lane >= 56) return;
  const int col = lane * 4;
  const bool act = (col < DDIM);
  float4 a[8];
#pragma unroll
  for (int j = 0; j < 8; ++j) a[j] = make_float4(0.f, 0.f, 0.f, 0.f);
  if (c < CSEG && act) {
    const int s = start[c], e = start[c + 1];
    for (int t = s; t < e; t += 8) {
      int   idx[8];
      float msk[8];
#pragma unroll
      for (int j = 0; j < 8; ++j) {
        const int tt = t + j;
        const bool ok = (tt < e);
        idx[j] = aid[ok ? tt : s];
        msk[j] = ok ? 1.f : 0.f;
      }
#pragma unroll
      for (int j = 0; j < 8; ++j) {
        const float4 v = *reinterpret_cast<const float4*>(
            embed + (size_t)idx[j] * DDIM + col);
        a[j].x = fmaf(msk[j], v.x, a[j].x);
        a[j].y = fmaf(msk[j], v.y, a[j].y);
        a[j].z = fmaf(msk[j], v.z, a[j].z);
        a[j].w = fmaf(msk[j], v.w, a[j].w);
      }
    }
#pragma unroll
    for (int j = 4; j < 8; ++j) {
      a[j - 4].x += a[j].x; a[j - 4].y += a[j].y;
      a[j - 4].z += a[j].z; a[j - 4].w += a[j].w;
    }
    a[0].x += a[1].x + a[2].x + a[3].x;
    a[0].y += a[1].y + a[2].y + a[3].y;
    a[0].z += a[1].z + a[2].z + a[3].z;
    a[0].w += a[1].w + a[2].w + a[3].w;
  }
  const ushort4 o = (c < CSEG && act)
      ? make_ushort4(f2bf(a[0].x), f2bf(a[0].y), f2bf(a[0].z), f2bf(a[0].w))
      : make_ushort4(0, 0, 0, 0);
  *reinterpret_cast<ushort4*>(Hb + (size_t)c * KPAD + col) = o;
}

// ---- XCD-aware block swizzle: 3128 = 8 XCDs * 391 ---------------------------
// XCD k gets contiguous work-ids -> ~98-ntile span shared by all 4 mtiles
// (Hb working set per XCD ~2.8 MB < 4 MB L2).
__device__ inline void gemm_block_map(int orig, int* ntile, int* mtile) {
  const int f = (orig & 7) * (GEMM_BLOCKS / 8) + (orig >> 3);
  *ntile = f >> 2;          // 0..781
  *mtile = f & 3;           // 0..3
}

// ---- GEMM tile: 8 waves, block tile 256(M) x 64(N), K=224 -------------------
// A-frags preloaded to regs (overlaps staging); B staged to LDS once per block.
__device__ inline void gemm_tile_lds(const u16* __restrict__ xb,
                                     const u16* __restrict__ Hb,
                                     u16* hlds, int m0, int n0, int tid,
                                     f32x4 acc[2][4]) {
  const int lane = tid & 63;
  const int r  = lane & 15;
  const int ko = (lane >> 4) * 8;
  const u16* xp = xb + (size_t)(m0 + r) * KPAD + ko;
  bf16x8 afrag[7][2];
#pragma unroll
  for (int ks = 0; ks < 7; ++ks) {
    afrag[ks][0] = *reinterpret_cast<const bf16x8*>(xp + ks * 32);
    afrag[ks][1] = *reinterpret_cast<const bf16x8*>(xp + 16 * KPAD + ks * 32);
  }
  // stage 64x224 bf16 B-tile: 1792 ushort8 chunks over 512 threads
#pragma unroll
  for (int k = 0; k < 4; ++k) {
    const int i = tid + k * 512;
    if (i < 1792) {
      const int row = i / 28, c8 = i % 28;
      const u16x8 h = *reinterpret_cast<const u16x8*>(
          Hb + (size_t)(n0 + row) * KPAD + c8 * 8);
      *reinterpret_cast<u16x8*>(hlds + row * LDSROW + c8 * 8) = h;
    }
  }
  __syncthreads();
#pragma unroll
  for (int ks = 0; ks < 7; ++ks) {
#pragma unroll
    for (int ni = 0; ni < 4; ++ni) {
      const bf16x8 b = *reinterpret_cast<const bf16x8*>(
          hlds + (r + ni * 16) * LDSROW + ko + ks * 32);
      acc[0][ni] = __builtin_amdgcn_mfma_f32_16x16x32_bf16(afrag[ks][0], b, acc[0][ni], 0, 0, 0);
      acc[1][ni] = __builtin_amdgcn_mfma_f32_16x16x32_bf16(afrag[ks][1], b, acc[1][ni], 0, 0, 0);
    }
  }
}

// ---- pass 1: per-row partial sums of exp(logit) over each N-tile ------------
__global__ __launch_bounds__(512) void gemm_pass1_kernel(const u16* __restrict__ xb,
                                                         const u16* __restrict__ Hb,
                                                         float* __restrict__ partials) {
  __shared__ u16 hlds[64 * LDSROW];
  int ntile, mtile;
  gemm_block_map(blockIdx.x, &ntile, &mtile);
  const int lane = threadIdx.x & 63, wave = threadIdx.x >> 6;
  const int m0 = mtile * 256 + wave * 32;
  const int n0 = ntile * NTILE;
  f32x4 acc[2][4] = {};
  gemm_tile_lds(xb, Hb, hlds, m0, n0, threadIdx.x, acc);
  const int cbase = n0 + (lane & 15);
#pragma unroll
  for (int mi = 0; mi < 2; ++mi) {
#pragma unroll
    for (int rr = 0; rr < 4; ++rr) {
      float s = 0.f;
#pragma unroll
      for (int ni = 0; ni < 4; ++ni) {
        if (cbase + ni * 16 < CSEG) s += __expf(acc[mi][ni][rr]);
      }
      for (int off = 1; off < 16; off <<= 1) s += __shfl_xor(s, off, 64);
      if ((lane & 15) == 0) {
        const int row = m0 + mi * 16 + (lane >> 4) * 4 + rr;
        partials[(size_t)row * NT + ntile] = s;
      }
    }
  }
}

// ---- reduce partial sums -> 1/rowsum ----------------------------------------
__global__ __launch_bounds__(256) void reduce_kernel(const float* __restrict__ partials,
                                                     float* __restrict__ invs) {
  const int row = blockIdx.x, tid = threadIdx.x;
  float s = 0.f;
  for (int nt = tid; nt < NT; nt += 256) s += partials[(size_t)row * NT + nt];
  __shared__ float sm[256];
  sm[tid] = s;
  __syncthreads();
  for (int st = 128; st > 0; st >>= 1) {
    if (tid < st) sm[tid] += sm[tid + st];
    __syncthreads();
  }
  if (tid == 0) invs[row] = 1.0f / sm[0];
}

// ---- pass 2: recompute logits, write exp(l) * inv to d_out (nontemporal) ----
__global__ __launch_bounds__(512) void gemm_pass2_kernel(const u16* __restrict__ xb,
                                                         const u16* __restrict__ Hb,
                                                         const float* __restrict__ invs,
                                                         float* __restrict__ out) {
  __shared__ u16 hlds[64 * LDSROW];
  int ntile, mtile;
  gemm_block_map(blockIdx.x, &ntile, &mtile);
  const int lane = threadIdx.x & 63, wave = threadIdx.x >> 6;
  const int m0 = mtile * 256 + wave * 32;
  const int n0 = ntile * NTILE;
  f32x4 acc[2][4] = {};
  gemm_tile_lds(xb, Hb, hlds, m0, n0, threadIdx.x, acc);
  const int c0 = n0 + (lane & 15);
#pragma unroll
  for (int mi = 0; mi < 2; ++mi) {
#pragma unroll
    for (int rr = 0; rr < 4; ++rr) {
      const int row = m0 + mi * 16 + (lane >> 4) * 4 + rr;
      const float inv = invs[row];
      float* orow = out + (size_t)row * CSEG;
#pragma unroll
      for (int ni = 0; ni < 4; ++ni) {
        const int col = c0 + ni * 16;
        if (col < CSEG) {
          __builtin_nontemporal_store(__expf(acc[mi][ni][rr]) * inv, &orow[col]);
        }
      }
    }
  }
}

extern "C" void kernel_launch(void* const* d_in, const int* in_sizes, int n_in,
                              void* d_out, int out_size, void* d_ws, size_t ws_size,
                              hipStream_t stream) {
  const float* x     = (const float*)d_in[0];
  const float* embed = (const float*)d_in[1];
  const int*   aid   = (const int*)d_in[2];
  const int*   sid   = (const int*)d_in[3];

  char* ws = (char*)d_ws;
  u16*   xb       = (u16*)(ws + WS_XB);
  u16*   Hb       = (u16*)(ws + WS_HB);
  float* partials = (float*)(ws + WS_PART);
  float* invs     = (float*)(ws + WS_INV);
  int*   start    = (int*)(ws + WS_START);
  u16*   ebf      = (u16*)(ws + WS_EBF);
  float* out      = (float*)d_out;

  const bool use_bf16 = (ws_size >= WS_TOTAL_BF16);

  hipLaunchKernelGGL(prep_all_kernel, dim3((TTOT + 255) / 256), dim3(256), 0, stream,
                     sid, start, x, xb, embed, ebf, use_bf16 ? 1 : 0);
  if (use_bf16) {
    hipLaunchKernelGGL(seg_sum_bf16_kernel, dim3(NPAD / 4), dim3(256), 0, stream,
                       ebf, aid, start, Hb);
  } else {
    hipLaunchKernelGGL(seg_sum_kernel, dim3(NPAD / 4), dim3(256), 0, stream,
                       embed, aid, start, Hb);
  }
  hipLaunchKernelGGL(gemm_pass1_kernel, dim3(GEMM_BLOCKS), dim3(512), 0, stream,
                     xb, Hb, partials);
  hipLaunchKernelGGL(reduce_kernel,     dim3(BROWS),       dim3(256), 0, stream,
                     partials, invs);
  hipLaunchKernelGGL(gemm_pass2_kernel, dim3(GEMM_BLOCKS), dim3(512), 0, stream,
                     xb, Hb, invs, out);
}

// Round 7
// 268.097 us; speedup vs baseline: 1.0346x; 1.0346x over previous
//
#include <hip/hip_runtime.h>
#include <hip/hip_bf16.h>

// Problem constants (fixed by the reference)
#define DDIM   200
#define CSEG   50000
#define TTOT   1000000
#define BROWS  1024
#define KPAD   224      // 7 * 32 (K padded for mfma 16x16x32)
#define NTILE  64
#define NT     782      // ceil(50000/64)
#define NPAD   50048    // NT*64
#define MTILES 8        // 1024 / 128
#define GEMM_BLOCKS (NT * MTILES)   // 6256 = 8 * 782 exactly
#define LDSROW 232      // padded LDS row stride (bf16 units): breaks bank conflicts

typedef __attribute__((ext_vector_type(8))) __bf16 bf16x8;
typedef __attribute__((ext_vector_type(4))) float  f32x4;
typedef unsigned short u16;
typedef __attribute__((ext_vector_type(8))) unsigned short u16x8;
typedef __attribute__((ext_vector_type(4))) unsigned short u16x4;

// ws layout (bytes)
#define WS_XB    0u
#define WS_HB    458752u
#define WS_PART  (WS_HB + 22421504u)
#define WS_INV   (WS_PART + 3203072u)
#define WS_START (WS_INV + 4096u)
#define WS_EBF   (WS_START + 200704u)
#define WS_TOTAL_BF16 ((size_t)WS_EBF + 160000000u)   // + bf16 embed table

__device__ inline u16 f2bf(float f) {
  unsigned u = __float_as_uint(f);
  u += 0x7FFFu + ((u >> 16) & 1u);   // round-to-nearest-even
  return (u16)(u >> 16);
}
__device__ inline float bf2f(u16 h) {
  return __uint_as_float(((unsigned)h) << 16);
}

// ---- fused: segment starts + x->bf16 + (optional) embed f32->bf16 -----------
__global__ __launch_bounds__(256) void prep_all_kernel(const int* __restrict__ sid,
                                                       int* __restrict__ start,
                                                       const float* __restrict__ x,
                                                       u16* __restrict__ xb,
                                                       const float* __restrict__ embed,
                                                       u16* __restrict__ ebf,
                                                       int do_conv) {
  const int gtid = blockIdx.x * 256 + threadIdx.x;
  // part 1: segment boundary detection (sorted sid)
  if (gtid < TTOT) {
    const int cur = sid[gtid];
    const int prev = (gtid == 0) ? -1 : sid[gtid - 1];
    for (int c = prev + 1; c <= cur; ++c) start[c] = gtid;
    if (gtid == TTOT - 1) {
      for (int c = cur + 1; c <= CSEG; ++c) start[c] = TTOT;
    }
  }
  // part 2: x -> bf16 K-padded
  if (gtid < BROWS * 56) {
    const int row = gtid / 56;
    const int col = (gtid % 56) * 4;
    ushort4 o = make_ushort4(0, 0, 0, 0);
    if (col < DDIM) {
      const float4 v = *reinterpret_cast<const float4*>(x + (size_t)row * DDIM + col);
      o = make_ushort4(f2bf(v.x), f2bf(v.y), f2bf(v.z), f2bf(v.w));
    }
    *reinterpret_cast<ushort4*>(xb + (size_t)row * KPAD + col) = o;
  }
  // part 3: embed table f32 -> bf16 (L3-resident afterwards), grid-stride
  if (do_conv) {
    const long long n4 = (long long)400000 * DDIM / 4;   // 20M float4
    const long long stride = (long long)gridDim.x * 256;
    for (long long i = gtid; i < n4; i += stride) {
      const f32x4 v = __builtin_nontemporal_load(reinterpret_cast<const f32x4*>(embed) + i);
      u16x4 o;
      o.x = f2bf(v.x); o.y = f2bf(v.y); o.z = f2bf(v.z); o.w = f2bf(v.w);
      *(reinterpret_cast<u16x4*>(ebf) + i) = o;
    }
  }
}

// ---- ragged gather (bf16 table) + segment sum -> Hb -------------------------
// v3: row-pair layout. Lanes 0-24 handle even rows, 25-49 odd rows, 16 B/lane.
// 8 ushort8 loads in flight per lane = 16 rows / 6.4 KB per wave.
__global__ __launch_bounds__(256) void seg_sum_bf16_kernel(const u16* __restrict__ ebf,
                                                           const int* __restrict__ aid,
                                                           const int* __restrict__ start,
                                                           u16* __restrict__ Hb) {
  const int wave = threadIdx.x >> 6;
  const int lane = threadIdx.x & 63;
  const int c = blockIdx.x * 4 + wave;
  if (c >= NPAD) return;
  const int chunk = (lane < 50) ? (lane % 25) : 0;   // 16 B chunk 0..24
  const int par   = (lane < 50) ? (lane / 25) : 0;   // row parity 0/1
  float acc[8] = {0.f, 0.f, 0.f, 0.f, 0.f, 0.f, 0.f, 0.f};
  if (c < CSEG && lane < 50) {
    const int s = start[c], e = start[c + 1];
    for (int tb = s; tb < e; tb += 16) {
      int   idx[8];
      float msk[8];
#pragma unroll
      for (int j = 0; j < 8; ++j) {
        const int tt = tb + 2 * j + par;
        const bool ok = (tt < e);
        idx[j] = aid[ok ? tt : s];
        msk[j] = ok ? 1.f : 0.f;
      }
#pragma unroll
      for (int j = 0; j < 8; ++j) {
        const u16x8 v = *reinterpret_cast<const u16x8*>(
            ebf + (size_t)idx[j] * DDIM + chunk * 8);
#pragma unroll
        for (int k = 0; k < 8; ++k) {
          acc[k] = fmaf(msk[j], bf2f(v[k]), acc[k]);
        }
      }
    }
  }
  // combine parities: lane l (<25) += lane l+25
  const int src = (lane + 25) & 63;
#pragma unroll
  for (int k = 0; k < 8; ++k) {
    acc[k] += __shfl(acc[k], src, 64);
  }
  // write: lanes 0-24 -> cols 0..199 ; lanes 25-27 -> zero pad cols 200..223
  if (lane < 28) {
    u16x8 o;
    if (lane < 25 && c < CSEG) {
#pragma unroll
      for (int k = 0; k < 8; ++k) o[k] = f2bf(acc[k]);
    } else {
#pragma unroll
      for (int k = 0; k < 8; ++k) o[k] = 0;
    }
    *reinterpret_cast<u16x8*>(Hb + (size_t)c * KPAD + lane * 8) = o;
  }
}

// ---- fallback f32 gather (ws too small for bf16 table) ----------------------
__global__ __launch_bounds__(256) void seg_sum_kernel(const float* __restrict__ embed,
                                                      const int* __restrict__ aid,
                                                      const int* __restrict__ start,
                                                      u16* __restrict__ Hb) {
  const int wave = threadIdx.x >> 6;
  const int lane = threadIdx.x & 63;
  const int c = blockIdx.x * 4 + wave;
  if (c >= NPAD || lane >= 56) return;
  const int col = lane * 4;
  const bool act = (col < DDIM);
  float4 a[8];
#pragma unroll
  for (int j = 0; j < 8; ++j) a[j] = make_float4(0.f, 0.f, 0.f, 0.f);
  if (c < CSEG && act) {
    const int s = start[c], e = start[c + 1];
    for (int t = s; t < e; t += 8) {
      int   idx[8];
      float msk[8];
#pragma unroll
      for (int j = 0; j < 8; ++j) {
        const int tt = t + j;
        const bool ok = (tt < e);
        idx[j] = aid[ok ? tt : s];
        msk[j] = ok ? 1.f : 0.f;
      }
#pragma unroll
      for (int j = 0; j < 8; ++j) {
        const float4 v = *reinterpret_cast<const float4*>(
            embed + (size_t)idx[j] * DDIM + col);
        a[j].x = fmaf(msk[j], v.x, a[j].x);
        a[j].y = fmaf(msk[j], v.y, a[j].y);
        a[j].z = fmaf(msk[j], v.z, a[j].z);
        a[j].w = fmaf(msk[j], v.w, a[j].w);
      }
    }
#pragma unroll
    for (int j = 4; j < 8; ++j) {
      a[j - 4].x += a[j].x; a[j - 4].y += a[j].y;
      a[j - 4].z += a[j].z; a[j - 4].w += a[j].w;
    }
    a[0].x += a[1].x + a[2].x + a[3].x;
    a[0].y += a[1].y + a[2].y + a[3].y;
    a[0].z += a[1].z + a[2].z + a[3].z;
    a[0].w += a[1].w + a[2].w + a[3].w;
  }
  const ushort4 o = (c < CSEG && act)
      ? make_ushort4(f2bf(a[0].x), f2bf(a[0].y), f2bf(a[0].z), f2bf(a[0].w))
      : make_ushort4(0, 0, 0, 0);
  *reinterpret_cast<ushort4*>(Hb + (size_t)c * KPAD + col) = o;
}

// ---- XCD-aware block swizzle ------------------------------------------------
__device__ inline void gemm_block_map(int orig, int* ntile, int* mtile) {
  const int f = (orig & 7) * (GEMM_BLOCKS / 8) + (orig >> 3);
  *ntile = f >> 3;
  *mtile = f & 7;
}

// ---- GEMM tile with LDS-staged B: 4 waves, 128(M) x 64(N), K=224 ------------
// A-frags preloaded to regs (overlaps staging); B staged once per block.
__device__ inline void gemm_tile_lds(const u16* __restrict__ xb,
                                     const u16* __restrict__ Hb,
                                     u16* hlds, int m0, int n0, int tid,
                                     f32x4 acc[2][4]) {
  const int lane = tid & 63;
  const int r  = lane & 15;
  const int ko = (lane >> 4) * 8;
  const u16* xp = xb + (size_t)(m0 + r) * KPAD + ko;
  bf16x8 afrag[7][2];
#pragma unroll
  for (int ks = 0; ks < 7; ++ks) {
    afrag[ks][0] = *reinterpret_cast<const bf16x8*>(xp + ks * 32);
    afrag[ks][1] = *reinterpret_cast<const bf16x8*>(xp + 16 * KPAD + ks * 32);
  }
  // stage 64x224 bf16 B-tile: 1792 ushort8 chunks, 7 per thread
#pragma unroll
  for (int k = 0; k < 7; ++k) {
    const int i = tid + k * 256;          // 0..1791
    const int row = i / 28, c8 = i % 28;  // 28 ushort8 per row
    const u16x8 h = *reinterpret_cast<const u16x8*>(
        Hb + (size_t)(n0 + row) * KPAD + c8 * 8);
    *reinterpret_cast<u16x8*>(hlds + row * LDSROW + c8 * 8) = h;
  }
  __syncthreads();
#pragma unroll
  for (int ks = 0; ks < 7; ++ks) {
#pragma unroll
    for (int ni = 0; ni < 4; ++ni) {
      const bf16x8 b = *reinterpret_cast<const bf16x8*>(
          hlds + (r + ni * 16) * LDSROW + ko + ks * 32);
      acc[0][ni] = __builtin_amdgcn_mfma_f32_16x16x32_bf16(afrag[ks][0], b, acc[0][ni], 0, 0, 0);
      acc[1][ni] = __builtin_amdgcn_mfma_f32_16x16x32_bf16(afrag[ks][1], b, acc[1][ni], 0, 0, 0);
    }
  }
}

// ---- pass 1: per-row partial sums of exp(logit) over each N-tile ------------
__global__ __launch_bounds__(256) void gemm_pass1_kernel(const u16* __restrict__ xb,
                                                         const u16* __restrict__ Hb,
                                                         float* __restrict__ partials) {
  __shared__ u16 hlds[64 * LDSROW];
  int ntile, mtile;
  gemm_block_map(blockIdx.x, &ntile, &mtile);
  const int lane = threadIdx.x & 63, wave = threadIdx.x >> 6;
  const int m0 = mtile * 128 + wave * 32;
  const int n0 = ntile * NTILE;
  f32x4 acc[2][4] = {};
  gemm_tile_lds(xb, Hb, hlds, m0, n0, threadIdx.x, acc);
  const int cbase = n0 + (lane & 15);
#pragma unroll
  for (int mi = 0; mi < 2; ++mi) {
#pragma unroll
    for (int rr = 0; rr < 4; ++rr) {
      float s = 0.f;
#pragma unroll
      for (int ni = 0; ni < 4; ++ni) {
        if (cbase + ni * 16 < CSEG) s += __expf(acc[mi][ni][rr]);
      }
      for (int off = 1; off < 16; off <<= 1) s += __shfl_xor(s, off, 64);
      if ((lane & 15) == 0) {
        const int row = m0 + mi * 16 + (lane >> 4) * 4 + rr;
        partials[(size_t)row * NT + ntile] = s;
      }
    }
  }
}

// ---- reduce partial sums -> 1/rowsum ----------------------------------------
__global__ __launch_bounds__(256) void reduce_kernel(const float* __restrict__ partials,
                                                     float* __restrict__ invs) {
  const int row = blockIdx.x, tid = threadIdx.x;
  float s = 0.f;
  for (int nt = tid; nt < NT; nt += 256) s += partials[(size_t)row * NT + nt];
  __shared__ float sm[256];
  sm[tid] = s;
  __syncthreads();
  for (int st = 128; st > 0; st >>= 1) {
    if (tid < st) sm[tid] += sm[tid + st];
    __syncthreads();
  }
  if (tid == 0) invs[row] = 1.0f / sm[0];
}

// ---- pass 2: recompute logits, write exp(l) * inv to d_out (nontemporal) ----
__global__ __launch_bounds__(256) void gemm_pass2_kernel(const u16* __restrict__ xb,
                                                         const u16* __restrict__ Hb,
                                                         const float* __restrict__ invs,
                                                         float* __restrict__ out) {
  __shared__ u16 hlds[64 * LDSROW];
  int ntile, mtile;
  gemm_block_map(blockIdx.x, &ntile, &mtile);
  const int lane = threadIdx.x & 63, wave = threadIdx.x >> 6;
  const int m0 = mtile * 128 + wave * 32;
  const int n0 = ntile * NTILE;
  f32x4 acc[2][4] = {};
  gemm_tile_lds(xb, Hb, hlds, m0, n0, threadIdx.x, acc);
  const int c0 = n0 + (lane & 15);
#pragma unroll
  for (int mi = 0; mi < 2; ++mi) {
#pragma unroll
    for (int rr = 0; rr < 4; ++rr) {
      const int row = m0 + mi * 16 + (lane >> 4) * 4 + rr;
      const float inv = invs[row];
      float* orow = out + (size_t)row * CSEG;
#pragma unroll
      for (int ni = 0; ni < 4; ++ni) {
        const int col = c0 + ni * 16;
        if (col < CSEG) {
          __builtin_nontemporal_store(__expf(acc[mi][ni][rr]) * inv, &orow[col]);
        }
      }
    }
  }
}

extern "C" void kernel_launch(void* const* d_in, const int* in_sizes, int n_in,
                              void* d_out, int out_size, void* d_ws, size_t ws_size,
                              hipStream_t stream) {
  const float* x     = (const float*)d_in[0];
  const float* embed = (const float*)d_in[1];
  const int*   aid   = (const int*)d_in[2];
  const int*   sid   = (const int*)d_in[3];

  char* ws = (char*)d_ws;
  u16*   xb       = (u16*)(ws + WS_XB);
  u16*   Hb       = (u16*)(ws + WS_HB);
  float* partials = (float*)(ws + WS_PART);
  float* invs     = (float*)(ws + WS_INV);
  int*   start    = (int*)(ws + WS_START);
  u16*   ebf      = (u16*)(ws + WS_EBF);
  float* out      = (float*)d_out;

  const bool use_bf16 = (ws_size >= WS_TOTAL_BF16);

  hipLaunchKernelGGL(prep_all_kernel, dim3((TTOT + 255) / 256), dim3(256), 0, stream,
                     sid, start, x, xb, embed, ebf, use_bf16 ? 1 : 0);
  if (use_bf16) {
    hipLaunchKernelGGL(seg_sum_bf16_kernel, dim3(NPAD / 4), dim3(256), 0, stream,
                       ebf, aid, start, Hb);
  } else {
    hipLaunchKernelGGL(seg_sum_kernel, dim3(NPAD / 4), dim3(256), 0, stream,
                       embed, aid, start, Hb);
  }
  hipLaunchKernelGGL(gemm_pass1_kernel, dim3(GEMM_BLOCKS), dim3(256), 0, stream,
                     xb, Hb, partials);
  hipLaunchKernelGGL(reduce_kernel,     dim3(BROWS),       dim3(256), 0, stream,
                     partials, invs);
  hipLaunchKernelGGL(gemm_pass2_kernel, dim3(GEMM_BLOCKS), dim3(256), 0, stream,
                     xb, Hb, invs, out);
}